// Round 13
// baseline (467.391 us; speedup 1.0000x reference)
//
#include <hip/hip_runtime.h>

// VQ-VAE vector quantizer, round 13: pure-VALU exact-fp32, zero-LDS hot loop.
// Finding from R3-R12: MFMA-bearing kernels are pinned at 93-125us with all pipes <20%
// busy; back-solved effective clock ~1 GHz (vs ~2.4 GHz for R1/R2 VALU kernels, which
// matched their issue models exactly). HIP-level structure (occupancy/spills/barriers/
// chain depth/instr count/prefetch) individually falsified. So: drop MFMA entirely.
// Design: 1 thread = 1 point; x[64] fully in VGPRs (static indexing via full unroll);
// distances d = 0.5||e||^2 - x.e in exact fp32 (same formula as the rescan all passing
// rounds trusted); e served 16 codes/chunk from a TRANSPOSED table Et[d][k] with
// wave-uniform addresses (scalarizable s_load / broadcast loads - no LDS pipe, R1's
// bottleneck). 16 independent FMA chains cover latency at 1 wave/SIMD.
// Model: ~160k cyc/SIMD ~ 67us @ 2.4 GHz.
// out (fp32 concat): [ loss(1) | quantized NCHW (4194304) | indices as float (65536) ]

#define DIMS   64
#define HW     4096
#define NPTS   65536
#define NCODES 1024
#define NPB    128                 // points (=threads) per block
#define QOFF   1
#define IOFF   (1 + NPTS * DIMS)

typedef unsigned int uint;

// ---- prep: Et[d][k] = emb[k][d] (transposed, fp32), hsq[k] = 0.5||e_k||^2, zero out[0]
__global__ void vq_prep(const float* __restrict__ emb, float* __restrict__ Et,
                        float* __restrict__ hsq, float* __restrict__ out)
{
    const int t = blockIdx.x * 256 + threadIdx.x;      // 0..16383
    if (t == 0) out[0] = 0.f;
    const int k = t & 1023, dg = t >> 10;              // code, dim-group of 4
    float4 v = ((const float4*)emb)[k * 16 + dg];      // emb[k][4dg..4dg+3]
    Et[(dg * 4 + 0) * 1024 + k] = v.x;                 // stores coalesced over k
    Et[(dg * 4 + 1) * 1024 + k] = v.y;
    Et[(dg * 4 + 2) * 1024 + k] = v.z;
    Et[(dg * 4 + 3) * 1024 + k] = v.w;
    if (t < NCODES) {
        const float4* r = (const float4*)(emb + (size_t)t * DIMS);
        float s = 0.f;
        #pragma unroll
        for (int i = 0; i < 16; ++i) {
            float4 e = r[i];
            s = fmaf(e.x, e.x, s); s = fmaf(e.y, e.y, s);
            s = fmaf(e.z, e.z, s); s = fmaf(e.w, e.w, s);
        }
        hsq[t] = 0.5f * s;
    }
}

__launch_bounds__(128)
__global__ void vq_main(const float* __restrict__ in, const float* __restrict__ emb,
                        const float* __restrict__ Et, const float* __restrict__ hsqw,
                        float* __restrict__ out)
{
    __shared__ float lred[2];

    const int tid = threadIdx.x;
    const int lane = tid & 63, w = tid >> 6;
    const int n0 = blockIdx.x * NPB;
    const int b = n0 >> 12, off = n0 & 4095;           // 128 | 4096: never crosses a batch
    const float* xp = in + (size_t)b * (DIMS * HW) + off + tid;

    // ---- x entirely in registers (static indices after full unroll)
    float x[64];
    #pragma unroll
    for (int d = 0; d < 64; ++d) x[d] = xp[d * HW];    // coalesced over threads

    float v1 = 1e30f; int i1 = 0;

    // ---- 64 chunks of 16 codes; all e/hsq addresses wave-uniform (scalarizable)
    for (int k0 = 0; k0 < NCODES; k0 += 16) {
        float acc[16];
        #pragma unroll
        for (int j = 0; j < 16; ++j) acc[j] = 0.f;

        #pragma unroll
        for (int d = 0; d < 64; ++d) {                 // 16 independent FMA chains
            const float4* er = (const float4*)(Et + d * 1024 + k0);
            float4 e0 = er[0], e1 = er[1], e2 = er[2], e3 = er[3];
            const float xd = x[d];
            acc[ 0] = fmaf(xd, e0.x, acc[ 0]); acc[ 1] = fmaf(xd, e0.y, acc[ 1]);
            acc[ 2] = fmaf(xd, e0.z, acc[ 2]); acc[ 3] = fmaf(xd, e0.w, acc[ 3]);
            acc[ 4] = fmaf(xd, e1.x, acc[ 4]); acc[ 5] = fmaf(xd, e1.y, acc[ 5]);
            acc[ 6] = fmaf(xd, e1.z, acc[ 6]); acc[ 7] = fmaf(xd, e1.w, acc[ 7]);
            acc[ 8] = fmaf(xd, e2.x, acc[ 8]); acc[ 9] = fmaf(xd, e2.y, acc[ 9]);
            acc[10] = fmaf(xd, e2.z, acc[10]); acc[11] = fmaf(xd, e2.w, acc[11]);
            acc[12] = fmaf(xd, e3.x, acc[12]); acc[13] = fmaf(xd, e3.y, acc[13]);
            acc[14] = fmaf(xd, e3.z, acc[14]); acc[15] = fmaf(xd, e3.w, acc[15]);
        }
        #pragma unroll
        for (int j = 0; j < 16; ++j) {                 // ascending k, strict <: first-min
            float dv = hsqw[k0 + j] - acc[j];
            if (dv < v1) { v1 = dv; i1 = k0 + j; }
        }
    }

    // ---- outputs: index, quantized gather-write, loss
    out[IOFF + n0 + tid] = (float)i1;
    const float* e = emb + (size_t)i1 * DIMS;
    float* oq = out + QOFF + (size_t)b * (DIMS * HW) + off + tid;
    float ls = 0.f;
    #pragma unroll
    for (int d = 0; d < 64; ++d) {
        float ev = e[d];                               // gather (L1/L2-hot 256 KB table)
        float df = ev - x[d];
        ls = fmaf(df, df, ls);
        oq[d * HW] = ev;                               // coalesced over threads
    }
    #pragma unroll
    for (int st = 32; st; st >>= 1) ls += __shfl_down(ls, st);
    if (lane == 0) lred[w] = ls;
    __syncthreads();
    if (tid == 0)
        atomicAdd(out, (lred[0] + lred[1]) * (0.25f / (float)(NPTS * DIMS)));
}

extern "C" void kernel_launch(void* const* d_in, const int* in_sizes, int n_in,
                              void* d_out, int out_size, void* d_ws, size_t ws_size,
                              hipStream_t stream) {
    const float* in  = (const float*)d_in[0];
    const float* emb = (const float*)d_in[1];
    float* out = (float*)d_out;
    float* Et  = (float*)d_ws;                         // 262144 B (transposed table)
    float* hsq = (float*)((char*)d_ws + 262144);       // 4096 B
    (void)in_sizes; (void)n_in; (void)out_size; (void)ws_size;

    vq_prep<<<64, 256, 0, stream>>>(emb, Et, hsq, out);   // also zeroes out[0]
    vq_main<<<NPTS / NPB, NPB, 0, stream>>>(in, emb, Et, hsq, out);
}